// Round 1
// baseline (169.794 us; speedup 1.0000x reference)
//
#include <hip/hip_runtime.h>

// YOLOv1 loss, MI355X. Memory-bound streaming reduction.
// y_pred: (16384,7,7,30) f32, y_true: (16384,7,7,6) f32, out: scalar f32.

#define CELLS  (16384 * 49)      // 802816 cells total
#define TILE   256               // cells per tile (= block threads)
#define NTILES (CELLS / TILE)    // 3136, exact (no tail)
#define NCH    30
#define NTR    6
#define LCOORD 5.0f
#define LNOOBJ 0.5f

__device__ __forceinline__ float iou_one(float x, float y, float w, float h,
                                         float t0, float t1, float t2, float t3) {
    float b1x1 = x - w * 0.5f, b1x2 = x + w * 0.5f;
    float b1y1 = y - h * 0.5f, b1y2 = y + h * 0.5f;
    float b2x1 = t0 - t2 * 0.5f, b2x2 = t0 + t2 * 0.5f;
    float b2y1 = t1 - t3 * 0.5f, b2y2 = t1 + t3 * 0.5f;
    float iw = fmaxf(fminf(b1x2, b2x2) - fmaxf(b1x1, b2x1), 0.0f);
    float ih = fmaxf(fminf(b1y2, b2y2) - fmaxf(b1y1, b2y1), 0.0f);
    float inter = iw * ih;
    float uni = w * h + t2 * t3 - inter;
    return inter / (uni + 1e-6f);
}

__global__ __launch_bounds__(256) void yolo_main(const float* __restrict__ yp,
                                                 const float* __restrict__ yt,
                                                 float* __restrict__ ws,
                                                 int ntiles_per_block_grid) {
    __shared__ float sp[TILE * NCH];   // 30 KiB
    __shared__ float st[TILE * NTR];   // 6 KiB
    __shared__ float red[4][8];

    const int tid = threadIdx.x;
    float v[6] = {0.f, 0.f, 0.f, 0.f, 0.f, 0.f};

    for (int tile = blockIdx.x; tile < NTILES; tile += gridDim.x) {
        // ---- stage tile: perfectly coalesced float4 loads ----
        const float4* gp4 = (const float4*)(yp + (size_t)tile * TILE * NCH);
        float4* sp4 = (float4*)sp;
        #pragma unroll
        for (int i = tid; i < TILE * NCH / 4; i += 256) sp4[i] = gp4[i];
        const float4* gt4 = (const float4*)(yt + (size_t)tile * TILE * NTR);
        float4* st4 = (float4*)st;
        for (int i = tid; i < TILE * NTR / 4; i += 256) st4[i] = gt4[i];
        __syncthreads();

        // ---- per-cell compute ----
        const float* p = sp + tid * NCH;
        const float* t = st + tid * NTR;
        float t0 = t[0], t1 = t[1], t2 = t[2], t3 = t[3], t4 = t[4];
        int lbl = (int)t[5];

        float iou0 = iou_one(p[0], p[1], p[2], p[3], t0, t1, t2, t3);
        float iou1 = iou_one(p[5], p[6], p[7], p[8], t0, t1, t2, t3);
        // jnp.argmax picks FIRST max on ties -> box1 wins only if strictly greater
        int base = (iou1 > iou0) ? 5 : 0;
        float tb0 = p[base + 0], tb1 = p[base + 1], tb2 = p[base + 2];
        float tb3 = p[base + 3], tb4 = p[base + 4];

        float obj = (t4 != 0.0f) ? 1.0f : 0.0f;
        float noobj = 1.0f - obj;

        float dx = tb0 - t0, dy = tb1 - t1;
        float a0 = obj * (dx * dx + dy * dy);

        float s2 = sqrtf(t2);                 // reference uses y_true[...,2] for BOTH
        float d2 = sqrtf(tb2) - s2;
        float d3 = sqrtf(tb3) - s2;
        float a1 = obj * (d2 * d2 + d3 * d3);

        float pc = fminf(fmaxf(tb4, 1e-7f), 1.0f - 1e-7f);
        float bce = -(t4 * logf(pc) + (1.0f - t4) * log1pf(-pc));
        float a2 = obj * bce;
        float a3 = noobj * bce;

        // log-softmax over 20 logits
        float m = p[10];
        #pragma unroll
        for (int k = 11; k < 30; ++k) m = fmaxf(m, p[k]);
        float se = 0.0f;
        #pragma unroll
        for (int k = 10; k < 30; ++k) se += expf(p[k] - m);
        float nll = logf(se) + m - p[10 + lbl];
        float a4 = obj * nll;

        v[0] += a0; v[1] += a1; v[2] += a2; v[3] += a3; v[4] += a4; v[5] += obj;
        __syncthreads();   // protect LDS before next tile's staging
    }

    // ---- wave reduce (64 lanes) ----
    #pragma unroll
    for (int j = 0; j < 6; ++j) {
        #pragma unroll
        for (int off = 32; off > 0; off >>= 1)
            v[j] += __shfl_down(v[j], off, 64);
    }
    const int wave = tid >> 6, lane = tid & 63;
    if (lane == 0) {
        #pragma unroll
        for (int j = 0; j < 6; ++j) red[wave][j] = v[j];
    }
    __syncthreads();
    if (tid == 0) {
        float* dst = ws + (size_t)blockIdx.x * 8;
        #pragma unroll
        for (int j = 0; j < 6; ++j)
            dst[j] = red[0][j] + red[1][j] + red[2][j] + red[3][j];
    }
}

__global__ __launch_bounds__(256) void yolo_final(const float* __restrict__ ws,
                                                  float* __restrict__ out,
                                                  int nblocks) {
    __shared__ float red[4][8];
    const int tid = threadIdx.x;
    float v[6] = {0.f, 0.f, 0.f, 0.f, 0.f, 0.f};
    for (int i = tid; i < nblocks; i += 256) {
        const float* src = ws + (size_t)i * 8;
        #pragma unroll
        for (int j = 0; j < 6; ++j) v[j] += src[j];
    }
    #pragma unroll
    for (int j = 0; j < 6; ++j) {
        #pragma unroll
        for (int off = 32; off > 0; off >>= 1)
            v[j] += __shfl_down(v[j], off, 64);
    }
    const int wave = tid >> 6, lane = tid & 63;
    if (lane == 0) {
        #pragma unroll
        for (int j = 0; j < 6; ++j) red[wave][j] = v[j];
    }
    __syncthreads();
    if (tid == 0) {
        float a[6];
        #pragma unroll
        for (int j = 0; j < 6; ++j)
            a[j] = red[0][j] + red[1][j] + red[2][j] + red[3][j];
        float n_obj = a[5];
        float n_noobj = (float)CELLS - n_obj;
        float loss = (LCOORD * (a[0] + a[1]) + a[2] + a[4]) / n_obj
                   + LNOOBJ * a[3] / n_noobj;
        out[0] = loss;
    }
}

extern "C" void kernel_launch(void* const* d_in, const int* in_sizes, int n_in,
                              void* d_out, int out_size, void* d_ws, size_t ws_size,
                              hipStream_t stream) {
    const float* yp = (const float*)d_in[0];  // (16384,7,7,30)
    const float* yt = (const float*)d_in[1];  // (16384,7,7,6)
    float* out = (float*)d_out;
    float* ws = (float*)d_ws;

    // One partial row (8 floats) per block. Degrade gracefully if ws is small.
    int nblocks = NTILES;
    size_t need = (size_t)nblocks * 8 * sizeof(float);
    if (ws_size < need) {
        nblocks = (int)(ws_size / (8 * sizeof(float)));
        if (nblocks > NTILES) nblocks = NTILES;
        if (nblocks < 1) nblocks = 1;
    }

    yolo_main<<<nblocks, 256, 0, stream>>>(yp, yt, ws, nblocks);
    yolo_final<<<1, 256, 0, stream>>>(ws, out, nblocks);
}